// Round 8
// baseline (71.110 us; speedup 1.0000x reference)
//
#include <hip/hip_runtime.h>

typedef __bf16 bf16x8 __attribute__((ext_vector_type(8)));
typedef float f32x4 __attribute__((ext_vector_type(4)));

#define S_LEN 2048
#define D_DIM 64
#define NHEAD 32

// ---------------- pre-pass: K -> bf16 [h][s][d], V -> bf16 transposed [h][d][s] ----------------
__global__ __launch_bounds__(256) void convert_kv(const float* __restrict__ K,
                                                  const float* __restrict__ V,
                                                  __bf16* __restrict__ Kb,
                                                  __bf16* __restrict__ Vtg) {
    const int head = blockIdx.y;              // 32
    const int s0   = blockIdx.x * 64;         // 32 chunks of 64 keys
    const int tr   = threadIdx.x >> 2;        // 0..63
    const int tc   = (threadIdx.x & 3) << 4;  // 0,16,32,48
    const size_t ib = (size_t)head * (S_LEN * D_DIM) + (size_t)(s0 + tr) * D_DIM + tc;

    __shared__ __bf16 tb[64][72];

    {   // K: straight convert, coalesced in/out
        const float* kr = K + ib;
        f32x4 a = *(const f32x4*)kr, b = *(const f32x4*)(kr + 4),
              c = *(const f32x4*)(kr + 8), d = *(const f32x4*)(kr + 12);
        bf16x8 o0, o1;
        #pragma unroll
        for (int e = 0; e < 4; ++e) {
            o0[e] = (__bf16)a[e]; o0[e + 4] = (__bf16)b[e];
            o1[e] = (__bf16)c[e]; o1[e + 4] = (__bf16)d[e];
        }
        __bf16* ko = Kb + ib;
        *(bf16x8*)ko = o0; *(bf16x8*)(ko + 8) = o1;
    }
    {   // V: transpose 64x64 tile via LDS
        const float* vr = V + ib;
        f32x4 a = *(const f32x4*)vr, b = *(const f32x4*)(vr + 4),
              c = *(const f32x4*)(vr + 8), d = *(const f32x4*)(vr + 12);
        #pragma unroll
        for (int e = 0; e < 4; ++e) {
            tb[tc +  e][tr] = (__bf16)a[e];
            tb[tc + 4 + e][tr] = (__bf16)b[e];
            tb[tc + 8 + e][tr] = (__bf16)c[e];
            tb[tc + 12 + e][tr] = (__bf16)d[e];
        }
    }
    __syncthreads();
    {   // write Vt rows: d = tr, keys s0+tc..+15
        bf16x8 o0, o1;
        #pragma unroll
        for (int e = 0; e < 8; ++e) { o0[e] = tb[tr][tc + e]; o1[e] = tb[tr][tc + 8 + e]; }
        __bf16* vo = Vtg + (size_t)head * (D_DIM * S_LEN) + (size_t)tr * S_LEN + s0 + tc;
        *(bf16x8*)vo = o0; *(bf16x8*)(vo + 8) = o1;
    }
}

// ---------------- main: flash attention, single-buffer LDS + reg-staged T14 ----------------
__global__ __launch_bounds__(256, 6) void attn_fwd(const float* __restrict__ Q,
                                                   const __bf16* __restrict__ Kb,
                                                   const __bf16* __restrict__ Vg,
                                                   float* __restrict__ O) {
    // 1024 blocks, 64-row chunks; XCD-locality chunk map (round-6).
    const int b    = blockIdx.x;
    const int xcd  = b & 7;
    const int cs   = (b >> 3) & 31;
    const int j    = b >> 8;                  // 0..3
    const int head = xcd * 4 + (cs >> 3);     // 4 heads per XCD
    const int slot = cs & 7;
    const int chunk = (j == 0) ? slot : (j == 1) ? (31 - slot)
                    : (j == 2) ? (slot + 8) : (23 - slot);   // 64-row q-chunk, 0..31

    const int tid  = threadIdx.x;
    const int wave = tid >> 6;
    const int lane = tid & 63;
    const int l15  = lane & 15;
    const int lhi  = lane >> 4;

    const int q0 = chunk * 64 + wave * 16;    // wave owns rows q0..q0+15
    const size_t qbase = (size_t)head * (S_LEN * D_DIM);
    const size_t vbase = (size_t)head * (D_DIM * S_LEN);
    const float qscale = 0.125f * 1.44269504088896340736f;   // D^-0.5 * log2(e)

    // single-buffered: 8K + 8K + 8K = 24 KB -> 6 blocks/CU
    __shared__ __align__(16) __bf16 Klds[64][64];   // [key][d], 16B-unit col ^ (key&7)
    __shared__ __align__(16) __bf16 Vt[64][64];     // [d][key], 16B-unit col ^ (d&7)
    __shared__ __align__(16) __bf16 Plds[4][16][64];

    // staging coords: thread covers row sr, 16B-units su0, su0+1
    const int sr  = tid >> 2;           // 0..63
    const int su0 = (tid & 3) << 1;     // 0,2,4,6
    const int sw0 = (su0 ^ (sr & 7)) << 3;        // element offset of stored unit 0
    const int sw1 = ((su0 + 1) ^ (sr & 7)) << 3;  // element offset of stored unit 1
    const __bf16* kSrc = Kb + qbase + (size_t)sr * D_DIM + su0 * 8;
    const __bf16* vSrc = Vg + vbase + (size_t)sr * S_LEN + su0 * 8;

    // ---- Q fragments (B-frag for swapped QK^T: col=l15, k=lhi*8+e) ----
    bf16x8 qf[2];
    {
        const float* qrow = Q + qbase + (size_t)(q0 + l15) * D_DIM + lhi * 8;
        #pragma unroll
        for (int h = 0; h < 2; ++h) {
            f32x4 a = *(const f32x4*)(qrow + h * 32);
            f32x4 bq = *(const f32x4*)(qrow + h * 32 + 4);
            bf16x8 t;
            #pragma unroll
            for (int e = 0; e < 4; ++e) { t[e] = (__bf16)(a[e] * qscale); t[e + 4] = (__bf16)(bq[e] * qscale); }
            qf[h] = t;
        }
    }

    f32x4 acc[4];
    #pragma unroll
    for (int td = 0; td < 4; ++td) acc[td] = (f32x4){0.f, 0.f, 0.f, 0.f};
    float m_r = -1e30f, l_r = 0.f;            // per-lane: q-row = q0 + l15

    // prefetch registers (tile data in flight)
    bf16x8 pK0, pK1, pV0, pV1;
    pK0 = *(const bf16x8*)kSrc;  pK1 = *(const bf16x8*)(kSrc + 8);
    pV0 = *(const bf16x8*)vSrc;  pV1 = *(const bf16x8*)(vSrc + 8);

    const int nt = chunk + 1;
    for (int kt = 0; kt < nt; ++kt) {
        __syncthreads();                      // all waves done computing previous tile

        // ---- write staged regs -> LDS (swizzled, bank-balanced) ----
        *(bf16x8*)&Klds[sr][sw0] = pK0;
        *(bf16x8*)&Klds[sr][sw1] = pK1;
        *(bf16x8*)&Vt[sr][sw0]   = pV0;
        *(bf16x8*)&Vt[sr][sw1]   = pV1;

        // ---- issue next tile's loads; latency hides under this tile's compute ----
        if (kt + 1 < nt) {
            const int kv1 = (kt + 1) << 6;
            const __bf16* kg = kSrc + (size_t)kv1 * D_DIM;
            const __bf16* vg = vSrc + kv1;
            pK0 = *(const bf16x8*)kg;  pK1 = *(const bf16x8*)(kg + 8);
            pV0 = *(const bf16x8*)vg;  pV1 = *(const bf16x8*)(vg + 8);
        }

        __syncthreads();                      // tile staged by all waves

        // ---- S^T = K Q^T : C/D col = q = l15, row = k = kv0 + ct*16 + lhi*4 + r ----
        f32x4 s[4];
        #pragma unroll
        for (int ct = 0; ct < 4; ++ct) s[ct] = (f32x4){0.f, 0.f, 0.f, 0.f};
        __builtin_amdgcn_s_setprio(1);
        #pragma unroll
        for (int h = 0; h < 2; ++h) {
            #pragma unroll
            for (int ct = 0; ct < 4; ++ct) {
                const int krow = ct * 16 + l15;
                bf16x8 kf = *(const bf16x8*)&Klds[krow][(h * 32 + lhi * 8) ^ ((l15 & 7) << 3)];
                s[ct] = __builtin_amdgcn_mfma_f32_16x16x32_bf16(kf, qf[h], s[ct], 0, 0, 0);
            }
        }
        __builtin_amdgcn_s_setprio(0);

        // ---- causal mask: only the last tile straddles the diagonal ----
        if (kt == nt - 1) {
            const int kv0 = kt << 6;
            const int qg = q0 + l15;
            #pragma unroll
            for (int ct = 0; ct < 4; ++ct)
                #pragma unroll
                for (int r = 0; r < 4; ++r) {
                    const int kg = kv0 + ct * 16 + lhi * 4 + r;
                    if (kg > qg) s[ct][r] = -1e30f;
                }
        }

        // ---- in-register online softmax (lane owns one q-row's 16 scores) ----
        float mm = fmaxf(fmaxf(fmaxf(s[0][0], s[0][1]), fmaxf(s[0][2], s[0][3])),
                         fmaxf(fmaxf(s[1][0], s[1][1]), fmaxf(s[1][2], s[1][3])));
        mm = fmaxf(mm, fmaxf(fmaxf(fmaxf(s[2][0], s[2][1]), fmaxf(s[2][2], s[2][3])),
                             fmaxf(fmaxf(s[3][0], s[3][1]), fmaxf(s[3][2], s[3][3]))));
        mm = fmaxf(mm, __shfl_xor(mm, 16));
        mm = fmaxf(mm, __shfl_xor(mm, 32));
        if (!__all(mm - m_r <= 8.0f)) {          // defer-max (T13): rescale rarely
            const float mn = fmaxf(m_r, mm);
            const float f = exp2f(m_r - mn);
            m_r = mn;
            l_r *= f;
            #pragma unroll
            for (int r = 0; r < 4; ++r) {
                const float fr = __shfl(f, lhi * 4 + r);   // factor for acc row q=lhi*4+r
                #pragma unroll
                for (int td = 0; td < 4; ++td) acc[td][r] *= fr;
            }
        }
        float ps = 0.f;
        #pragma unroll
        for (int ct = 0; ct < 4; ++ct)
            #pragma unroll
            for (int r = 0; r < 4; ++r) {
                const float p = exp2f(s[ct][r] - m_r);
                s[ct][r] = p;
                ps += p;
            }
        ps += __shfl_xor(ps, 16);
        ps += __shfl_xor(ps, 32);
        l_r += ps;

        // ---- P (S^T layout) -> per-wave LDS (swizzled b64 writes) -> A-frags ----
        #pragma unroll
        for (int ct = 0; ct < 4; ++ct) {
            union { __bf16 h[4]; unsigned long long u; } pw;
            #pragma unroll
            for (int r = 0; r < 4; ++r) pw.h[r] = (__bf16)s[ct][r];
            *(unsigned long long*)&Plds[wave][l15][(ct * 16 + lhi * 4) ^ ((l15 & 7) << 3)] = pw.u;
        }
        asm volatile("s_waitcnt lgkmcnt(0)" ::: "memory");
        bf16x8 pf[2];
        #pragma unroll
        for (int kh = 0; kh < 2; ++kh)
            pf[kh] = *(const bf16x8*)&Plds[wave][l15][(kh * 32 + lhi * 8) ^ ((l15 & 7) << 3)];
        asm volatile("" ::: "memory");

        // ---- O += P V ----
        __builtin_amdgcn_s_setprio(1);
        #pragma unroll
        for (int kh = 0; kh < 2; ++kh) {
            #pragma unroll
            for (int td = 0; td < 4; ++td) {
                const int vrow = td * 16 + l15;
                bf16x8 vf = *(const bf16x8*)&Vt[vrow][(kh * 32 + lhi * 8) ^ ((vrow & 7) << 3)];
                acc[td] = __builtin_amdgcn_mfma_f32_16x16x32_bf16(pf[kh], vf, acc[td], 0, 0, 0);
            }
        }
        __builtin_amdgcn_s_setprio(0);
    }

    // ---- epilogue: O = acc / l  (l for row q=lhi*4+r lives on lane lhi*4+r) ----
    float* orow = O + qbase + (size_t)q0 * D_DIM;
    #pragma unroll
    for (int r = 0; r < 4; ++r) {
        const float inv = 1.0f / __shfl(l_r, lhi * 4 + r);
        #pragma unroll
        for (int td = 0; td < 4; ++td)
            orow[(size_t)(lhi * 4 + r) * D_DIM + td * 16 + l15] = acc[td][r] * inv;
    }
}

// ---------------- fallback (fp32 in-kernel staging) if ws too small ----------------
__global__ __launch_bounds__(256, 4) void attn_fwd_fb(const float* __restrict__ Q,
                                                      const float* __restrict__ K,
                                                      const float* __restrict__ V,
                                                      float* __restrict__ O) {
    const int b    = blockIdx.x;
    const int xcd  = b & 7;
    const int cs   = (b >> 3) & 31;
    const int j    = b >> 8;
    const int head = xcd * 4 + (cs >> 3);
    const int slot = cs & 7;
    const int chunk = (j == 0) ? slot : (j == 1) ? (31 - slot)
                    : (j == 2) ? (slot + 8) : (23 - slot);

    const int tid  = threadIdx.x;
    const int wave = tid >> 6;
    const int lane = tid & 63;
    const int l15  = lane & 15;
    const int lhi  = lane >> 4;

    const int q0 = chunk * 64 + wave * 16;
    const size_t base = (size_t)head * (S_LEN * D_DIM);
    const float qscale = 0.125f * 1.44269504088896340736f;

    __shared__ __align__(16) __bf16 Klds[2][64][64];
    __shared__ __align__(16) __bf16 Vt[2][64][64];
    __shared__ __align__(16) __bf16 Plds[4][16][64];

    const int rk = tid >> 2;
    const int ck = (tid & 3) << 4;
    const int kp = tid & 31;
    const int dc = tid >> 5;
    const int swk = (rk & 7) << 3;

    bf16x8 qf[2];
    {
        const float* qrow = Q + base + (size_t)(q0 + l15) * D_DIM + lhi * 8;
        #pragma unroll
        for (int h = 0; h < 2; ++h) {
            f32x4 a = *(const f32x4*)(qrow + h * 32);
            f32x4 bq = *(const f32x4*)(qrow + h * 32 + 4);
            bf16x8 t;
            #pragma unroll
            for (int e = 0; e < 4; ++e) { t[e] = (__bf16)(a[e] * qscale); t[e + 4] = (__bf16)(bq[e] * qscale); }
            qf[h] = t;
        }
    }

    f32x4 acc[4];
    #pragma unroll
    for (int td = 0; td < 4; ++td) acc[td] = (f32x4){0.f, 0.f, 0.f, 0.f};
    float m_r = -1e30f, l_r = 0.f;

    f32x4 pk[4], pva[2], pvb[2];
    {
        const float* ks = K + base + (size_t)rk * D_DIM + ck;
        #pragma unroll
        for (int i = 0; i < 4; ++i) pk[i] = *(const f32x4*)(ks + 4 * i);
        const float* v0 = V + base + (size_t)(2 * kp) * D_DIM + dc * 8;
        pva[0] = *(const f32x4*)v0;           pva[1] = *(const f32x4*)(v0 + 4);
        pvb[0] = *(const f32x4*)(v0 + D_DIM); pvb[1] = *(const f32x4*)(v0 + D_DIM + 4);
        bf16x8 k0, k1;
        #pragma unroll
        for (int e = 0; e < 4; ++e) {
            k0[e] = (__bf16)pk[0][e]; k0[e + 4] = (__bf16)pk[1][e];
            k1[e] = (__bf16)pk[2][e]; k1[e + 4] = (__bf16)pk[3][e];
        }
        *(bf16x8*)&Klds[0][rk][ck ^ swk] = k0;
        *(bf16x8*)&Klds[0][rk][(ck + 8) ^ swk] = k1;
        #pragma unroll
        for (int jj = 0; jj < 8; ++jj) {
            const int d = dc * 8 + jj;
            const float av = (jj < 4) ? pva[0][jj & 3] : pva[1][jj & 3];
            const float bv = (jj < 4) ? pvb[0][jj & 3] : pvb[1][jj & 3];
            union { __bf16 h[2]; unsigned int u; } t;
            t.h[0] = (__bf16)av; t.h[1] = (__bf16)bv;
            *(unsigned int*)&Vt[0][d][(2 * kp) ^ ((d & 7) << 3)] = t.u;
        }
    }

    const int nt = chunk + 1;
    for (int kt = 0; kt < nt; ++kt) {
        const int cur = kt & 1;
        __syncthreads();
        const bool pre = (kt + 1 < nt);
        if (pre) {
            const int kv1 = (kt + 1) << 6;
            const float* ks = K + base + (size_t)(kv1 + rk) * D_DIM + ck;
            #pragma unroll
            for (int i = 0; i < 4; ++i) pk[i] = *(const f32x4*)(ks + 4 * i);
            const float* v0 = V + base + (size_t)(kv1 + 2 * kp) * D_DIM + dc * 8;
            pva[0] = *(const f32x4*)v0;           pva[1] = *(const f32x4*)(v0 + 4);
            pvb[0] = *(const f32x4*)(v0 + D_DIM); pvb[1] = *(const f32x4*)(v0 + D_DIM + 4);
        }

        f32x4 s[4];
        #pragma unroll
        for (int ct = 0; ct < 4; ++ct) s[ct] = (f32x4){0.f, 0.f, 0.f, 0.f};
        #pragma unroll
        for (int h = 0; h < 2; ++h) {
            #pragma unroll
            for (int ct = 0; ct < 4; ++ct) {
                const int krow = ct * 16 + l15;
                bf16x8 kf = *(const bf16x8*)&Klds[cur][krow][(h * 32 + lhi * 8) ^ ((l15 & 7) << 3)];
                s[ct] = __builtin_amdgcn_mfma_f32_16x16x32_bf16(kf, qf[h], s[ct], 0, 0, 0);
            }
        }

        if (kt == nt - 1) {
            const int kv0 = kt << 6;
            const int qg = q0 + l15;
            #pragma unroll
            for (int ct = 0; ct < 4; ++ct)
                #pragma unroll
                for (int r = 0; r < 4; ++r) {
                    const int kg = kv0 + ct * 16 + lhi * 4 + r;
                    if (kg > qg) s[ct][r] = -1e30f;
                }
        }

        float mm = fmaxf(fmaxf(fmaxf(s[0][0], s[0][1]), fmaxf(s[0][2], s[0][3])),
                         fmaxf(fmaxf(s[1][0], s[1][1]), fmaxf(s[1][2], s[1][3])));
        mm = fmaxf(mm, fmaxf(fmaxf(fmaxf(s[2][0], s[2][1]), fmaxf(s[2][2], s[2][3])),
                             fmaxf(fmaxf(s[3][0], s[3][1]), fmaxf(s[3][2], s[3][3]))));
        mm = fmaxf(mm, __shfl_xor(mm, 16));
        mm = fmaxf(mm, __shfl_xor(mm, 32));
        if (!__all(mm - m_r <= 8.0f)) {
            const float mn = fmaxf(m_r, mm);
            const float f = exp2f(m_r - mn);
            m_r = mn;
            l_r *= f;
            #pragma unroll
            for (int r = 0; r < 4; ++r) {
                const float fr = __shfl(f, lhi * 4 + r);
                #pragma unroll
                for (int td = 0; td < 4; ++td) acc[td][r] *= fr;
            }
        }
        float ps = 0.f;
        #pragma unroll
        for (int ct = 0; ct < 4; ++ct)
            #pragma unroll
            for (int r = 0; r < 4; ++r) {
                const float p = exp2f(s[ct][r] - m_r);
                s[ct][r] = p;
                ps += p;
            }
        ps += __shfl_xor(ps, 16);
        ps += __shfl_xor(ps, 32);
        l_r += ps;

        #pragma unroll
        for (int ct = 0; ct < 4; ++ct) {
            union { __bf16 h[4]; unsigned long long u; } pw;
            #pragma unroll
            for (int r = 0; r < 4; ++r) pw.h[r] = (__bf16)s[ct][r];
            *(unsigned long long*)&Plds[wave][l15][(ct * 16 + lhi * 4) ^ ((l15 & 7) << 3)] = pw.u;
        }
        asm volatile("s_waitcnt lgkmcnt(0)" ::: "memory");
        bf16x8 pf[2];
        #pragma unroll
        for (int kh = 0; kh < 2; ++kh)
            pf[kh] = *(const bf16x8*)&Plds[wave][l15][(kh * 32 + lhi * 8) ^ ((l15 & 7) << 3)];
        asm volatile("" ::: "memory");

        #pragma unroll
        for (int kh = 0; kh < 2; ++kh) {
            #pragma unroll
            for (int td = 0; td < 4; ++td) {
                const int vrow = td * 16 + l15;
                bf16x8 vf = *(const bf16x8*)&Vt[cur][vrow][(kh * 32 + lhi * 8) ^ ((vrow & 7) << 3)];
                acc[td] = __builtin_amdgcn_mfma_f32_16x16x32_bf16(pf[kh], vf, acc[td], 0, 0, 0);
            }
        }

        if (pre) {
            const int nxt = cur ^ 1;
            bf16x8 k0, k1;
            #pragma unroll
            for (int e = 0; e < 4; ++e) {
                k0[e] = (__bf16)pk[0][e]; k0[e + 4] = (__bf16)pk[1][e];
                k1[e] = (__bf16)pk[2][e]; k1[e + 4] = (__bf16)pk[3][e];
            }
            *(bf16x8*)&Klds[nxt][rk][ck ^ swk] = k0;
            *(bf16x8*)&Klds[nxt][rk][(ck + 8) ^ swk] = k1;
            #pragma unroll
            for (int jj = 0; jj < 8; ++jj) {
                const int d = dc * 8 + jj;
                const float av = (jj < 4) ? pva[0][jj & 3] : pva[1][jj & 3];
                const float bv = (jj < 4) ? pvb[0][jj & 3] : pvb[1][jj & 3];
                union { __bf16 h[2]; unsigned int u; } t;
                t.h[0] = (__bf16)av; t.h[1] = (__bf16)bv;
                *(unsigned int*)&Vt[nxt][d][(2 * kp) ^ ((d & 7) << 3)] = t.u;
            }
        }
    }

    float* orow = O + base + (size_t)q0 * D_DIM;
    #pragma unroll
    for (int r = 0; r < 4; ++r) {
        const float inv = 1.0f / __shfl(l_r, lhi * 4 + r);
        #pragma unroll
        for (int td = 0; td < 4; ++td)
            orow[(size_t)(lhi * 4 + r) * D_DIM + td * 16 + l15] = acc[td][r] * inv;
    }
}

extern "C" void kernel_launch(void* const* d_in, const int* in_sizes, int n_in,
                              void* d_out, int out_size, void* d_ws, size_t ws_size,
                              hipStream_t stream) {
    const float* q = (const float*)d_in[0];
    const float* k = (const float*)d_in[1];
    const float* v = (const float*)d_in[2];
    float* o = (float*)d_out;
    const size_t elems = (size_t)NHEAD * S_LEN * D_DIM;
    if (ws_size >= 2 * elems * sizeof(__bf16)) {
        __bf16* Kb  = (__bf16*)d_ws;
        __bf16* Vtg = Kb + elems;
        convert_kv<<<dim3(32, 32), dim3(256), 0, stream>>>(k, v, Kb, Vtg);
        attn_fwd<<<dim3(1024), dim3(256), 0, stream>>>(q, Kb, Vtg, o);
    } else {
        attn_fwd_fb<<<dim3(1024), dim3(256), 0, stream>>>(q, k, v, o);
    }
}

// Round 9
// 64.865 us; speedup vs baseline: 1.0963x; 1.0963x over previous
//
#include <hip/hip_runtime.h>

typedef __bf16 bf16x8 __attribute__((ext_vector_type(8)));
typedef float f32x4 __attribute__((ext_vector_type(4)));

#define S_LEN 2048
#define D_DIM 64
#define NHEAD 32

typedef __attribute__((address_space(1))) const void gas;
typedef __attribute__((address_space(3))) void las;

// 48 jobs per head, descending cost (LPT): pack = chunk | t0<<5 | nt<<10.
// Chunks 0..15 unsplit; chunks 16..31 split at h=(c+2)/2 into [0,h) + [h,c+1).
#define J(c, t0, nt) ((unsigned short)((c) | ((t0) << 5) | ((nt) << 10)))
__device__ const unsigned short JOBS[48] = {
    J(15,0,16), J(30,0,16), J(31,0,16), J(31,16,16),
    J(14,0,15), J(28,0,15), J(29,0,15), J(29,15,15), J(30,16,15),
    J(13,0,14), J(26,0,14), J(27,0,14), J(27,14,14), J(28,15,14),
    J(12,0,13), J(24,0,13), J(25,0,13), J(25,13,13), J(26,14,13),
    J(11,0,12), J(22,0,12), J(23,0,12), J(23,12,12), J(24,13,12),
    J(10,0,11), J(20,0,11), J(21,0,11), J(21,11,11), J(22,12,11),
    J( 9,0,10), J(18,0,10), J(19,0,10), J(19,10,10), J(20,11,10),
    J( 8,0, 9), J(16,0, 9), J(17,0, 9), J(17, 9, 9), J(18,10, 9),
    J( 7,0, 8), J(16,9, 8),
    J( 6,0, 7), J( 5,0, 6), J( 4,0, 5), J( 3,0, 4), J( 2,0, 3), J( 1,0, 2), J( 0,0, 1)
};
#define PART_FLOATS 4224   // 64 m + 64 l + 64*64 acc

// ---------------- pre-pass: K -> bf16 [h][s][d], V -> bf16 transposed [h][d][s] ----------------
__global__ __launch_bounds__(256) void convert_kv(const float* __restrict__ K,
                                                  const float* __restrict__ V,
                                                  __bf16* __restrict__ Kb,
                                                  __bf16* __restrict__ Vtg) {
    const int head = blockIdx.y;
    const int s0   = blockIdx.x * 64;
    const int tr   = threadIdx.x >> 2;
    const int tc   = (threadIdx.x & 3) << 4;
    const size_t ib = (size_t)head * (S_LEN * D_DIM) + (size_t)(s0 + tr) * D_DIM + tc;

    __shared__ __bf16 tb[64][72];

    {   // K: straight convert
        const float* kr = K + ib;
        f32x4 a = *(const f32x4*)kr, b = *(const f32x4*)(kr + 4),
              c = *(const f32x4*)(kr + 8), d = *(const f32x4*)(kr + 12);
        bf16x8 o0, o1;
        #pragma unroll
        for (int e = 0; e < 4; ++e) {
            o0[e] = (__bf16)a[e]; o0[e + 4] = (__bf16)b[e];
            o1[e] = (__bf16)c[e]; o1[e + 4] = (__bf16)d[e];
        }
        __bf16* ko = Kb + ib;
        *(bf16x8*)ko = o0; *(bf16x8*)(ko + 8) = o1;
    }
    {   // V: transpose 64x64 tile via LDS
        const float* vr = V + ib;
        f32x4 a = *(const f32x4*)vr, b = *(const f32x4*)(vr + 4),
              c = *(const f32x4*)(vr + 8), d = *(const f32x4*)(vr + 12);
        #pragma unroll
        for (int e = 0; e < 4; ++e) {
            tb[tc +  e][tr] = (__bf16)a[e];
            tb[tc + 4 + e][tr] = (__bf16)b[e];
            tb[tc + 8 + e][tr] = (__bf16)c[e];
            tb[tc + 12 + e][tr] = (__bf16)d[e];
        }
    }
    __syncthreads();
    {
        bf16x8 o0, o1;
        #pragma unroll
        for (int e = 0; e < 8; ++e) { o0[e] = tb[tr][tc + e]; o1[e] = tb[tr][tc + 8 + e]; }
        __bf16* vo = Vtg + (size_t)head * (D_DIM * S_LEN) + (size_t)tr * S_LEN + s0 + tc;
        *(bf16x8*)vo = o0; *(bf16x8*)(vo + 8) = o1;
    }
}

// ---------------- main: flash attention, DMA-staged bf16 K/V ----------------
// SPLIT=0: 1024 blocks, round-6 chunk map, full chunks, O written directly.
// SPLIT=1: 1536 blocks, LPT job table; split chunks write fp32 partials.
template <int SPLIT>
__global__ __launch_bounds__(256, 4) void attn_fwd(const float* __restrict__ Q,
                                                   const __bf16* __restrict__ Kb,
                                                   const __bf16* __restrict__ Vg,
                                                   float* __restrict__ O,
                                                   float* __restrict__ Ppart) {
    int head, chunk, t0, nt;
    if constexpr (SPLIT) {
        const int b   = blockIdx.x;            // 1536
        const int xcd = b & 7;
        const int w   = b >> 3;                // 0..191
        head = xcd * 4 + (w & 3);              // 4 heads per XCD
        const unsigned short jj = JOBS[w >> 2];
        chunk = jj & 31; t0 = (jj >> 5) & 31; nt = jj >> 10;
    } else {
        const int b    = blockIdx.x;           // 1024
        const int xcd  = b & 7;
        const int cs   = (b >> 3) & 31;
        const int j    = b >> 8;
        head = xcd * 4 + (cs >> 3);
        const int slot = cs & 7;
        chunk = (j == 0) ? slot : (j == 1) ? (31 - slot)
              : (j == 2) ? (slot + 8) : (23 - slot);
        t0 = 0; nt = chunk + 1;
    }
    const bool diagJob = (t0 + nt - 1 == chunk);

    const int tid  = threadIdx.x;
    const int wave = tid >> 6;
    const int lane = tid & 63;
    const int l15  = lane & 15;
    const int lhi  = lane >> 4;

    const int q0 = chunk * 64 + wave * 16;     // wave owns rows q0..q0+15
    const size_t qbase = (size_t)head * (S_LEN * D_DIM);
    const size_t vbase = (size_t)head * (D_DIM * S_LEN);
    const float qscale = 0.125f * 1.44269504088896340736f;   // D^-0.5 * log2(e)

    __shared__ __align__(16) __bf16 Klds[2][64][64];   // [buf][key][d], 16B-unit col ^ (key&7)
    __shared__ __align__(16) __bf16 Vt[2][64][64];     // [buf][d][key], 16B-unit col ^ (d&7)
    __shared__ __align__(16) __bf16 Plds[4][16][64];

    // per-lane pre-swizzled gload_lds source offsets (row base always = 0 mod 8)
    const int xsw = (lane & 7) ^ ((lane >> 3) & 7);
    const size_t kOff = (size_t)(lane >> 3) * D_DIM + (size_t)xsw * 8;
    const size_t vOff = (size_t)(lane >> 3) * S_LEN + (size_t)xsw * 8;
    const __bf16* kgw = Kb + qbase + (size_t)(wave * 16) * D_DIM + kOff;
    const __bf16* vgw = Vg + vbase + (size_t)(wave * 16) * S_LEN + vOff;

    // ---- Q fragments (B-frag for swapped QK^T: col=l15, k=lhi*8+e) ----
    bf16x8 qf[2];
    {
        const float* qrow = Q + qbase + (size_t)(q0 + l15) * D_DIM + lhi * 8;
        #pragma unroll
        for (int h = 0; h < 2; ++h) {
            f32x4 a = *(const f32x4*)(qrow + h * 32);
            f32x4 bq = *(const f32x4*)(qrow + h * 32 + 4);
            bf16x8 t;
            #pragma unroll
            for (int e = 0; e < 4; ++e) { t[e] = (__bf16)(a[e] * qscale); t[e + 4] = (__bf16)(bq[e] * qscale); }
            qf[h] = t;
        }
    }

    f32x4 acc[4];
    #pragma unroll
    for (int td = 0; td < 4; ++td) acc[td] = (f32x4){0.f, 0.f, 0.f, 0.f};
    float m_r = -1e30f, l_r = 0.f;             // per-lane: q-row = q0 + l15

    auto stage = [&](int kv0, int bufi) {
        const __bf16* kg = kgw + (size_t)kv0 * D_DIM;
        const __bf16* vg = vgw + kv0;
        __builtin_amdgcn_global_load_lds((gas*)kg,               (las*)&Klds[bufi][wave * 16][0],     16, 0, 0);
        __builtin_amdgcn_global_load_lds((gas*)(kg + 8 * D_DIM), (las*)&Klds[bufi][wave * 16 + 8][0], 16, 0, 0);
        __builtin_amdgcn_global_load_lds((gas*)vg,               (las*)&Vt[bufi][wave * 16][0],       16, 0, 0);
        __builtin_amdgcn_global_load_lds((gas*)(vg + 8 * S_LEN), (las*)&Vt[bufi][wave * 16 + 8][0],   16, 0, 0);
    };

    stage(t0 << 6, 0);

    for (int kt = 0; kt < nt; ++kt) {
        const int cur = kt & 1;
        asm volatile("s_waitcnt vmcnt(0)" ::: "memory");
        __syncthreads();                       // buf[cur] fully staged by all waves

        if (kt + 1 < nt) stage((t0 + kt + 1) << 6, cur ^ 1);
        const int kv0 = (t0 + kt) << 6;

        // ---- S^T = K Q^T ----
        f32x4 s[4];
        #pragma unroll
        for (int ct = 0; ct < 4; ++ct) s[ct] = (f32x4){0.f, 0.f, 0.f, 0.f};
        __builtin_amdgcn_s_setprio(1);
        #pragma unroll
        for (int h = 0; h < 2; ++h) {
            #pragma unroll
            for (int ct = 0; ct < 4; ++ct) {
                const int krow = ct * 16 + l15;
                bf16x8 kf = *(const bf16x8*)&Klds[cur][krow][(h * 32 + lhi * 8) ^ ((l15 & 7) << 3)];
                s[ct] = __builtin_amdgcn_mfma_f32_16x16x32_bf16(kf, qf[h], s[ct], 0, 0, 0);
            }
        }
        __builtin_amdgcn_s_setprio(0);

        // ---- causal mask: only the diagonal-owning job's last tile ----
        if (diagJob && kt == nt - 1) {
            const int qg = q0 + l15;
            #pragma unroll
            for (int ct = 0; ct < 4; ++ct)
                #pragma unroll
                for (int r = 0; r < 4; ++r) {
                    const int kg = kv0 + ct * 16 + lhi * 4 + r;
                    if (kg > qg) s[ct][r] = -1e30f;
                }
        }

        // ---- in-register online softmax ----
        float mm = fmaxf(fmaxf(fmaxf(s[0][0], s[0][1]), fmaxf(s[0][2], s[0][3])),
                         fmaxf(fmaxf(s[1][0], s[1][1]), fmaxf(s[1][2], s[1][3])));
        mm = fmaxf(mm, fmaxf(fmaxf(fmaxf(s[2][0], s[2][1]), fmaxf(s[2][2], s[2][3])),
                             fmaxf(fmaxf(s[3][0], s[3][1]), fmaxf(s[3][2], s[3][3]))));
        mm = fmaxf(mm, __shfl_xor(mm, 16));
        mm = fmaxf(mm, __shfl_xor(mm, 32));
        if (!__all(mm - m_r <= 8.0f)) {        // defer-max: rescale rarely
            const float mn = fmaxf(m_r, mm);
            const float f = exp2f(m_r - mn);
            m_r = mn;
            l_r *= f;
            #pragma unroll
            for (int r = 0; r < 4; ++r) {
                const float fr = __shfl(f, lhi * 4 + r);
                #pragma unroll
                for (int td = 0; td < 4; ++td) acc[td][r] *= fr;
            }
        }
        float ps = 0.f;
        #pragma unroll
        for (int ct = 0; ct < 4; ++ct)
            #pragma unroll
            for (int r = 0; r < 4; ++r) {
                const float p = exp2f(s[ct][r] - m_r);
                s[ct][r] = p;
                ps += p;
            }
        ps += __shfl_xor(ps, 16);
        ps += __shfl_xor(ps, 32);
        l_r += ps;

        // ---- P (S^T layout) -> per-wave LDS (swizzled b64 writes) -> A-frags ----
        #pragma unroll
        for (int ct = 0; ct < 4; ++ct) {
            union { __bf16 h[4]; unsigned long long u; } pw;
            #pragma unroll
            for (int r = 0; r < 4; ++r) pw.h[r] = (__bf16)s[ct][r];
            *(unsigned long long*)&Plds[wave][l15][(ct * 16 + lhi * 4) ^ ((l15 & 7) << 3)] = pw.u;
        }
        asm volatile("s_waitcnt lgkmcnt(0)" ::: "memory");
        bf16x8 pf[2];
        #pragma unroll
        for (int kh = 0; kh < 2; ++kh)
            pf[kh] = *(const bf16x8*)&Plds[wave][l15][(kh * 32 + lhi * 8) ^ ((l15 & 7) << 3)];
        asm volatile("" ::: "memory");

        // ---- O += P V ----
        __builtin_amdgcn_s_setprio(1);
        #pragma unroll
        for (int kh = 0; kh < 2; ++kh) {
            #pragma unroll
            for (int td = 0; td < 4; ++td) {
                const int vrow = td * 16 + l15;
                bf16x8 vf = *(const bf16x8*)&Vt[cur][vrow][(kh * 32 + lhi * 8) ^ ((vrow & 7) << 3)];
                acc[td] = __builtin_amdgcn_mfma_f32_16x16x32_bf16(pf[kh], vf, acc[td], 0, 0, 0);
            }
        }
        __builtin_amdgcn_s_setprio(0);
    }

    // ---- epilogue ----
    if (!SPLIT || chunk < 16) {                // full chunk: O = acc / l
        float* orow = O + qbase + (size_t)q0 * D_DIM;
        #pragma unroll
        for (int r = 0; r < 4; ++r) {
            const float inv = 1.0f / __shfl(l_r, lhi * 4 + r);
            #pragma unroll
            for (int td = 0; td < 4; ++td)
                orow[(size_t)(lhi * 4 + r) * D_DIM + td * 16 + l15] = acc[td][r] * inv;
        }
    } else {                                   // split segment: raw partials
        const int seg = (t0 != 0) ? 1 : 0;
        float* pp = Ppart + (size_t)(head * 32 + (chunk - 16) * 2 + seg) * PART_FLOATS;
        if (lhi == 0) {
            pp[wave * 16 + l15] = m_r;
            pp[64 + wave * 16 + l15] = l_r;
        }
        #pragma unroll
        for (int r = 0; r < 4; ++r)
            #pragma unroll
            for (int td = 0; td < 4; ++td)
                pp[128 + (size_t)(wave * 16 + lhi * 4 + r) * 64 + td * 16 + l15] = acc[td][r];
    }
}

// ---------------- combine: merge the two partials of each split chunk ----------------
__global__ __launch_bounds__(256) void combine(const float* __restrict__ Ppart,
                                               float* __restrict__ O) {
    const int head = blockIdx.y;               // 32
    const int ch   = blockIdx.x;               // 0..15 -> chunk 16+ch
    const float* PA = Ppart + (size_t)(head * 32 + ch * 2) * PART_FLOATS;
    const float* PB = PA + PART_FLOATS;
    const int row = threadIdx.x >> 2;          // 0..63
    const int c0  = (threadIdx.x & 3) << 4;    // 0,16,32,48

    const float mA = PA[row], lA = PA[64 + row];
    const float mB = PB[row], lB = PB[64 + row];
    const float M  = fmaxf(mA, mB);
    const float wA = exp2f(mA - M), wB = exp2f(mB - M);
    const float inv = 1.0f / (lA * wA + lB * wB);

    const float* a = PA + 128 + (size_t)row * 64 + c0;
    const float* b = PB + 128 + (size_t)row * 64 + c0;
    float* o = O + (size_t)head * (S_LEN * D_DIM) + (size_t)((16 + ch) * 64 + row) * D_DIM + c0;
    #pragma unroll
    for (int i = 0; i < 4; ++i) {
        f32x4 va = *(const f32x4*)(a + 4 * i);
        f32x4 vb = *(const f32x4*)(b + 4 * i);
        f32x4 vo;
        #pragma unroll
        for (int e = 0; e < 4; ++e) vo[e] = (va[e] * wA + vb[e] * wB) * inv;
        *(f32x4*)(o + 4 * i) = vo;
    }
}

// ---------------- fallback (fp32 in-kernel staging) if ws too small ----------------
__global__ __launch_bounds__(256, 4) void attn_fwd_fb(const float* __restrict__ Q,
                                                      const float* __restrict__ K,
                                                      const float* __restrict__ V,
                                                      float* __restrict__ O) {
    const int b    = blockIdx.x;
    const int xcd  = b & 7;
    const int cs   = (b >> 3) & 31;
    const int j    = b >> 8;
    const int head = xcd * 4 + (cs >> 3);
    const int slot = cs & 7;
    const int chunk = (j == 0) ? slot : (j == 1) ? (31 - slot)
                    : (j == 2) ? (slot + 8) : (23 - slot);

    const int tid  = threadIdx.x;
    const int wave = tid >> 6;
    const int lane = tid & 63;
    const int l15  = lane & 15;
    const int lhi  = lane >> 4;

    const int q0 = chunk * 64 + wave * 16;
    const size_t base = (size_t)head * (S_LEN * D_DIM);
    const float qscale = 0.125f * 1.44269504088896340736f;

    __shared__ __align__(16) __bf16 Klds[2][64][64];
    __shared__ __align__(16) __bf16 Vt[2][64][64];
    __shared__ __align__(16) __bf16 Plds[4][16][64];

    const int rk = tid >> 2;
    const int ck = (tid & 3) << 4;
    const int kp = tid & 31;
    const int dc = tid >> 5;
    const int swk = (rk & 7) << 3;

    bf16x8 qf[2];
    {
        const float* qrow = Q + base + (size_t)(q0 + l15) * D_DIM + lhi * 8;
        #pragma unroll
        for (int h = 0; h < 2; ++h) {
            f32x4 a = *(const f32x4*)(qrow + h * 32);
            f32x4 bq = *(const f32x4*)(qrow + h * 32 + 4);
            bf16x8 t;
            #pragma unroll
            for (int e = 0; e < 4; ++e) { t[e] = (__bf16)(a[e] * qscale); t[e + 4] = (__bf16)(bq[e] * qscale); }
            qf[h] = t;
        }
    }

    f32x4 acc[4];
    #pragma unroll
    for (int td = 0; td < 4; ++td) acc[td] = (f32x4){0.f, 0.f, 0.f, 0.f};
    float m_r = -1e30f, l_r = 0.f;

    f32x4 pk[4], pva[2], pvb[2];
    {
        const float* ks = K + base + (size_t)rk * D_DIM + ck;
        #pragma unroll
        for (int i = 0; i < 4; ++i) pk[i] = *(const f32x4*)(ks + 4 * i);
        const float* v0 = V + base + (size_t)(2 * kp) * D_DIM + dc * 8;
        pva[0] = *(const f32x4*)v0;           pva[1] = *(const f32x4*)(v0 + 4);
        pvb[0] = *(const f32x4*)(v0 + D_DIM); pvb[1] = *(const f32x4*)(v0 + D_DIM + 4);
        bf16x8 k0, k1;
        #pragma unroll
        for (int e = 0; e < 4; ++e) {
            k0[e] = (__bf16)pk[0][e]; k0[e + 4] = (__bf16)pk[1][e];
            k1[e] = (__bf16)pk[2][e]; k1[e + 4] = (__bf16)pk[3][e];
        }
        *(bf16x8*)&Klds[0][rk][ck ^ swk] = k0;
        *(bf16x8*)&Klds[0][rk][(ck + 8) ^ swk] = k1;
        #pragma unroll
        for (int jj = 0; jj < 8; ++jj) {
            const int d = dc * 8 + jj;
            const float av = (jj < 4) ? pva[0][jj & 3] : pva[1][jj & 3];
            const float bv = (jj < 4) ? pvb[0][jj & 3] : pvb[1][jj & 3];
            union { __bf16 h[2]; unsigned int u; } t;
            t.h[0] = (__bf16)av; t.h[1] = (__bf16)bv;
            *(unsigned int*)&Vt[0][d][(2 * kp) ^ ((d & 7) << 3)] = t.u;
        }
    }

    const int nt = chunk + 1;
    for (int kt = 0; kt < nt; ++kt) {
        const int cur = kt & 1;
        __syncthreads();
        const bool pre = (kt + 1 < nt);
        if (pre) {
            const int kv1 = (kt + 1) << 6;
            const float* ks = K + base + (size_t)(kv1 + rk) * D_DIM + ck;
            #pragma unroll
            for (int i = 0; i < 4; ++i) pk[i] = *(const f32x4*)(ks + 4 * i);
            const float* v0 = V + base + (size_t)(kv1 + 2 * kp) * D_DIM + dc * 8;
            pva[0] = *(const f32x4*)v0;           pva[1] = *(const f32x4*)(v0 + 4);
            pvb[0] = *(const f32x4*)(v0 + D_DIM); pvb[1] = *(const f32x4*)(v0 + D_DIM + 4);
        }

        f32x4 s[4];
        #pragma unroll
        for (int ct = 0; ct < 4; ++ct) s[ct] = (f32x4){0.f, 0.f, 0.f, 0.f};
        #pragma unroll
        for (int h = 0; h < 2; ++h) {
            #pragma unroll
            for (int ct = 0; ct < 4; ++ct) {
                const int krow = ct * 16 + l15;
                bf16x8 kf = *(const bf16x8*)&Klds[cur][krow][(h * 32 + lhi * 8) ^ ((l15 & 7) << 3)];
                s[ct] = __builtin_amdgcn_mfma_f32_16x16x32_bf16(kf, qf[h], s[ct], 0, 0, 0);
            }
        }

        if (kt == nt - 1) {
            const int kv0 = kt << 6;
            const int qg = q0 + l15;
            #pragma unroll
            for (int ct = 0; ct < 4; ++ct)
                #pragma unroll
                for (int r = 0; r < 4; ++r) {
                    const int kg = kv0 + ct * 16 + lhi * 4 + r;
                    if (kg > qg) s[ct][r] = -1e30f;
                }
        }

        float mm = fmaxf(fmaxf(fmaxf(s[0][0], s[0][1]), fmaxf(s[0][2], s[0][3])),
                         fmaxf(fmaxf(s[1][0], s[1][1]), fmaxf(s[1][2], s[1][3])));
        mm = fmaxf(mm, fmaxf(fmaxf(fmaxf(s[2][0], s[2][1]), fmaxf(s[2][2], s[2][3])),
                             fmaxf(fmaxf(s[3][0], s[3][1]), fmaxf(s[3][2], s[3][3]))));
        mm = fmaxf(mm, __shfl_xor(mm, 16));
        mm = fmaxf(mm, __shfl_xor(mm, 32));
        if (!__all(mm - m_r <= 8.0f)) {
            const float mn = fmaxf(m_r, mm);
            const float f = exp2f(m_r - mn);
            m_r = mn;
            l_r *= f;
            #pragma unroll
            for (int r = 0; r < 4; ++r) {
                const float fr = __shfl(f, lhi * 4 + r);
                #pragma unroll
                for (int td = 0; td < 4; ++td) acc[td][r] *= fr;
            }
        }
        float ps = 0.f;
        #pragma unroll
        for (int ct = 0; ct < 4; ++ct)
            #pragma unroll
            for (int r = 0; r < 4; ++r) {
                const float p = exp2f(s[ct][r] - m_r);
                s[ct][r] = p;
                ps += p;
            }
        ps += __shfl_xor(ps, 16);
        ps += __shfl_xor(ps, 32);
        l_r += ps;

        #pragma unroll
        for (int ct = 0; ct < 4; ++ct) {
            union { __bf16 h[4]; unsigned long long u; } pw;
            #pragma unroll
            for (int r = 0; r < 4; ++r) pw.h[r] = (__bf16)s[ct][r];
            *(unsigned long long*)&Plds[wave][l15][(ct * 16 + lhi * 4) ^ ((l15 & 7) << 3)] = pw.u;
        }
        asm volatile("s_waitcnt lgkmcnt(0)" ::: "memory");
        bf16x8 pf[2];
        #pragma unroll
        for (int kh = 0; kh < 2; ++kh)
            pf[kh] = *(const bf16x8*)&Plds[wave][l15][(kh * 32 + lhi * 8) ^ ((l15 & 7) << 3)];
        asm volatile("" ::: "memory");

        #pragma unroll
        for (int kh = 0; kh < 2; ++kh) {
            #pragma unroll
            for (int td = 0; td < 4; ++td) {
                const int vrow = td * 16 + l15;
                bf16x8 vf = *(const bf16x8*)&Vt[cur][vrow][(kh * 32 + lhi * 8) ^ ((vrow & 7) << 3)];
                acc[td] = __builtin_amdgcn_mfma_f32_16x16x32_bf16(pf[kh], vf, acc[td], 0, 0, 0);
            }
        }

        if (pre) {
            const int nxt = cur ^ 1;
            bf16x8 k0, k1;
            #pragma unroll
            for (int e = 0; e < 4; ++e) {
                k0[e] = (__bf16)pk[0][e]; k0[e + 4] = (__bf16)pk[1][e];
                k1[e] = (__bf16)pk[2][e]; k1[e + 4] = (__bf16)pk[3][e];
            }
            *(bf16x8*)&Klds[nxt][rk][ck ^ swk] = k0;
            *(bf16x8*)&Klds[nxt][rk][(ck + 8) ^ swk] = k1;
            #pragma unroll
            for (int jj = 0; jj < 8; ++jj) {
                const int d = dc * 8 + jj;
                const float av = (jj < 4) ? pva[0][jj & 3] : pva[1][jj & 3];
                const float bv = (jj < 4) ? pvb[0][jj & 3] : pvb[1][jj & 3];
                union { __bf16 h[2]; unsigned int u; } t;
                t.h[0] = (__bf16)av; t.h[1] = (__bf16)bv;
                *(unsigned int*)&Vt[nxt][d][(2 * kp) ^ ((d & 7) << 3)] = t.u;
            }
        }
    }

    float* orow = O + base + (size_t)q0 * D_DIM;
    #pragma unroll
    for (int r = 0; r < 4; ++r) {
        const float inv = 1.0f / __shfl(l_r, lhi * 4 + r);
        #pragma unroll
        for (int td = 0; td < 4; ++td)
            orow[(size_t)(lhi * 4 + r) * D_DIM + td * 16 + l15] = acc[td][r] * inv;
    }
}

extern "C" void kernel_launch(void* const* d_in, const int* in_sizes, int n_in,
                              void* d_out, int out_size, void* d_ws, size_t ws_size,
                              hipStream_t stream) {
    const float* q = (const float*)d_in[0];
    const float* k = (const float*)d_in[1];
    const float* v = (const float*)d_in[2];
    float* o = (float*)d_out;
    const size_t elems = (size_t)NHEAD * S_LEN * D_DIM;
    const size_t kvBytes = 2 * elems * sizeof(__bf16);                       // 16 MB
    const size_t partBytes = (size_t)NHEAD * 32 * PART_FLOATS * sizeof(float); // ~17.3 MB
    if (ws_size >= kvBytes + partBytes) {
        __bf16* Kb  = (__bf16*)d_ws;
        __bf16* Vtg = Kb + elems;
        float* Pp   = (float*)((char*)d_ws + kvBytes);
        convert_kv<<<dim3(32, 32), dim3(256), 0, stream>>>(k, v, Kb, Vtg);
        attn_fwd<1><<<dim3(1536), dim3(256), 0, stream>>>(q, Kb, Vtg, o, Pp);
        combine<<<dim3(16, 32), dim3(256), 0, stream>>>(Pp, o);
    } else if (ws_size >= kvBytes) {
        __bf16* Kb  = (__bf16*)d_ws;
        __bf16* Vtg = Kb + elems;
        convert_kv<<<dim3(32, 32), dim3(256), 0, stream>>>(k, v, Kb, Vtg);
        attn_fwd<0><<<dim3(1024), dim3(256), 0, stream>>>(q, Kb, Vtg, o, nullptr);
    } else {
        attn_fwd_fb<<<dim3(1024), dim3(256), 0, stream>>>(q, k, v, o);
    }
}

// Round 10
// 62.683 us; speedup vs baseline: 1.1344x; 1.0348x over previous
//
#include <hip/hip_runtime.h>

typedef __bf16 bf16x8 __attribute__((ext_vector_type(8)));
typedef float f32x4 __attribute__((ext_vector_type(4)));
typedef float f32x16 __attribute__((ext_vector_type(16)));

#define S_LEN 2048
#define D_DIM 64
#define NHEAD 32
#define PART_FLOATS 8448   // 128 m + 128 l + 128*64 acc

typedef __attribute__((address_space(1))) const void gas;
typedef __attribute__((address_space(3))) void las;

// 24 jobs/head (128-row chunks; chunks 8..15 split in half), grouped into 8
// CU-triples of exactly 34 tiles each. TRIP[trip*3 + pass].
#define J(c, t0, nt) ((unsigned short)((c) | ((t0) << 4) | ((nt) << 9)))
__device__ const unsigned short TRIP[24] = {
    J(15,0,16), J(15,16,16), J(0,0,2),
    J(7,0,16),  J(13,0,14),  J(1,0,4),
    J(14,0,15), J(12,0,13),  J(2,0,6),
    J(14,15,15),J(10,0,11),  J(3,0,8),
    J(13,14,14),J(10,11,11), J(8,0,9),
    J(6,0,14),  J(9,0,10),   J(9,10,10),
    J(12,13,13),J(11,0,12),  J(8,9,9),
    J(11,12,12),J(5,0,12),   J(4,0,10),
};

// ---------------- pre-pass: K -> bf16 [h][s][d], V -> bf16 transposed [h][d][s] ----------------
__global__ __launch_bounds__(256) void convert_kv(const float* __restrict__ K,
                                                  const float* __restrict__ V,
                                                  __bf16* __restrict__ Kb,
                                                  __bf16* __restrict__ Vtg) {
    const int head = blockIdx.y;
    const int s0   = blockIdx.x * 64;
    const int tr   = threadIdx.x >> 2;
    const int tc   = (threadIdx.x & 3) << 4;
    const size_t ib = (size_t)head * (S_LEN * D_DIM) + (size_t)(s0 + tr) * D_DIM + tc;

    __shared__ __bf16 tb[64][72];

    {   // K: straight convert
        const float* kr = K + ib;
        f32x4 a = *(const f32x4*)kr, b = *(const f32x4*)(kr + 4),
              c = *(const f32x4*)(kr + 8), d = *(const f32x4*)(kr + 12);
        bf16x8 o0, o1;
        #pragma unroll
        for (int e = 0; e < 4; ++e) {
            o0[e] = (__bf16)a[e]; o0[e + 4] = (__bf16)b[e];
            o1[e] = (__bf16)c[e]; o1[e + 4] = (__bf16)d[e];
        }
        __bf16* ko = Kb + ib;
        *(bf16x8*)ko = o0; *(bf16x8*)(ko + 8) = o1;
    }
    {   // V: transpose 64x64 tile via LDS
        const float* vr = V + ib;
        f32x4 a = *(const f32x4*)vr, b = *(const f32x4*)(vr + 4),
              c = *(const f32x4*)(vr + 8), d = *(const f32x4*)(vr + 12);
        #pragma unroll
        for (int e = 0; e < 4; ++e) {
            tb[tc +  e][tr] = (__bf16)a[e];
            tb[tc + 4 + e][tr] = (__bf16)b[e];
            tb[tc + 8 + e][tr] = (__bf16)c[e];
            tb[tc + 12 + e][tr] = (__bf16)d[e];
        }
    }
    __syncthreads();
    {
        bf16x8 o0, o1;
        #pragma unroll
        for (int e = 0; e < 8; ++e) { o0[e] = tb[tr][tc + e]; o1[e] = tb[tr][tc + 8 + e]; }
        __bf16* vo = Vtg + (size_t)head * (D_DIM * S_LEN) + (size_t)tr * S_LEN + s0 + tc;
        *(bf16x8*)vo = o0; *(bf16x8*)(vo + 8) = o1;
    }
}

// ---------------- main: 32x32 MFMA flash attention, in-register P (T12) ----------------
__global__ __launch_bounds__(256, 3) void attn32(const float* __restrict__ Q,
                                                 const __bf16* __restrict__ Kb,
                                                 const __bf16* __restrict__ Vg,
                                                 float* __restrict__ O,
                                                 float* __restrict__ Pp) {
    // 768 blocks = 256 CU-slots x 3 passes; each CU-slot's triple sums to 34 tiles.
    const int b    = blockIdx.x;
    const int xcd  = b & 7;
    const int cu   = (b >> 3) & 31;
    const int pass = b >> 8;                  // 0..2
    const int head = xcd * 4 + (cu >> 3);     // 4 heads per XCD
    const unsigned short jw = TRIP[(cu & 7) * 3 + pass];
    const int chunk = jw & 15;                // 128-row q-chunk
    const int t0    = (jw >> 4) & 31;         // first 64-key tile
    const int nt    = jw >> 9;                // tile count

    const int tid  = threadIdx.x;
    const int wave = tid >> 6;
    const int lane = tid & 63;
    const int l31  = lane & 31;
    const int hi   = lane >> 5;
    const int sw31 = (l31 & 7) << 3;

    const int q0w = chunk * 128 + wave * 32;  // wave owns q rows q0w..q0w+31
    const size_t qbase = (size_t)head * (S_LEN * D_DIM);
    const size_t vbase = (size_t)head * (D_DIM * S_LEN);
    const float qscale = 0.125f * 1.44269504088896340736f;   // D^-0.5 * log2(e)

    __shared__ __align__(16) __bf16 Klds[2][64][64];   // [buf][key][d], 16B-unit col ^ (key&7)
    __shared__ __align__(16) __bf16 Vt[2][64][64];     // [buf][d][key], 16B-unit col ^ (d&7)

    // per-lane pre-swizzled gload_lds source offsets
    const int xsw = (lane & 7) ^ ((lane >> 3) & 7);
    const size_t kOff = (size_t)(lane >> 3) * D_DIM + (size_t)xsw * 8;
    const size_t vOff = (size_t)(lane >> 3) * S_LEN + (size_t)xsw * 8;
    const __bf16* kgw = Kb + qbase + (size_t)(wave * 16) * D_DIM + kOff;
    const __bf16* vgw = Vg + vbase + (size_t)(wave * 16) * S_LEN + vOff;

    // ---- Q B-frags (swapped QK^T): col=q=l31, k-dim d = kd*16 + hi*8 + e ----
    bf16x8 qf[4];
    {
        const float* qrow = Q + qbase + (size_t)(q0w + l31) * D_DIM + hi * 8;
        #pragma unroll
        for (int kd = 0; kd < 4; ++kd) {
            f32x4 a = *(const f32x4*)(qrow + kd * 16);
            f32x4 c = *(const f32x4*)(qrow + kd * 16 + 4);
            bf16x8 t;
            #pragma unroll
            for (int e = 0; e < 4; ++e) { t[e] = (__bf16)(a[e] * qscale); t[e + 4] = (__bf16)(c[e] * qscale); }
            qf[kd] = t;
        }
    }

    f32x16 acc0 = {0.f}, acc1 = {0.f};        // O[q=crow(r,hi)][d = l31 (+32 for acc1)]
    #pragma unroll
    for (int r = 0; r < 16; ++r) { acc0[r] = 0.f; acc1[r] = 0.f; }
    float m_r = -1e30f, l_r = 0.f;            // per-lane: q-row = q0w + l31

    auto stage = [&](int kv0, int bufi) {
        const __bf16* kg = kgw + (size_t)kv0 * D_DIM;
        const __bf16* vg = vgw + kv0;
        __builtin_amdgcn_global_load_lds((gas*)kg,               (las*)&Klds[bufi][wave * 16][0],     16, 0, 0);
        __builtin_amdgcn_global_load_lds((gas*)(kg + 8 * D_DIM), (las*)&Klds[bufi][wave * 16 + 8][0], 16, 0, 0);
        __builtin_amdgcn_global_load_lds((gas*)vg,               (las*)&Vt[bufi][wave * 16][0],       16, 0, 0);
        __builtin_amdgcn_global_load_lds((gas*)(vg + 8 * S_LEN), (las*)&Vt[bufi][wave * 16 + 8][0],   16, 0, 0);
    };
    auto cvtpk = [](float lo, float hh) {
        unsigned int r;
        asm("v_cvt_pk_bf16_f32 %0, %1, %2" : "=v"(r) : "v"(lo), "v"(hh));
        return r;
    };

    stage(t0 << 6, 0);

    for (int it = 0; it < nt; ++it) {
        const int cur = it & 1;
        asm volatile("s_waitcnt vmcnt(0)" ::: "memory");
        __syncthreads();                      // buf[cur] fully staged by all waves

        if (it + 1 < nt) stage((t0 + it + 1) << 6, cur ^ 1);
        const int kv0 = (t0 + it) << 6;

        if (kv0 <= q0w + 31) {                // wave has unmasked work this tile
            // ---- S^T = K Q^T (32x32): lane holds 32 scores of q-row q0w+l31 ----
            f32x16 s0, s1;
            #pragma unroll
            for (int r = 0; r < 16; ++r) { s0[r] = 0.f; s1[r] = 0.f; }
            __builtin_amdgcn_s_setprio(1);
            #pragma unroll
            for (int kd = 0; kd < 4; ++kd) {
                bf16x8 kf0 = *(const bf16x8*)&Klds[cur][l31][(kd * 16 + hi * 8) ^ sw31];
                bf16x8 kf1 = *(const bf16x8*)&Klds[cur][32 + l31][(kd * 16 + hi * 8) ^ sw31];
                s0 = __builtin_amdgcn_mfma_f32_32x32x16_bf16(kf0, qf[kd], s0, 0, 0, 0);
                s1 = __builtin_amdgcn_mfma_f32_32x32x16_bf16(kf1, qf[kd], s1, 0, 0, 0);
            }
            __builtin_amdgcn_s_setprio(0);

            // ---- causal mask (diagonal-straddling tiles only) ----
            if (kv0 + 63 > q0w) {
                const int qg = q0w + l31;
                #pragma unroll
                for (int r = 0; r < 16; ++r) {
                    const int cr = (r & 3) + 8 * (r >> 2) + 4 * hi;
                    if (kv0 + cr > qg)      s0[r] = -1e30f;
                    if (kv0 + 32 + cr > qg) s1[r] = -1e30f;
                }
            }

            // ---- in-lane online softmax (31 fmax + 1 shuffle) ----
            float mm = -1e30f;
            #pragma unroll
            for (int r = 0; r < 16; ++r) mm = fmaxf(mm, fmaxf(s0[r], s1[r]));
            mm = fmaxf(mm, __shfl_xor(mm, 32));
            if (!__all(mm - m_r <= 8.0f)) {   // defer-max: rescale rarely
                const float mn = fmaxf(m_r, mm);
                const float f = exp2f(m_r - mn);
                m_r = mn;
                l_r *= f;
                #pragma unroll
                for (int r = 0; r < 16; ++r) {
                    const float fr = __shfl(f, (r & 3) + 8 * (r >> 2) + 4 * hi);
                    acc0[r] *= fr; acc1[r] *= fr;
                }
            }
            float ps = 0.f, ps2 = 0.f;
            #pragma unroll
            for (int r = 0; r < 16; ++r) {
                s0[r] = exp2f(s0[r] - m_r); ps  += s0[r];
                s1[r] = exp2f(s1[r] - m_r); ps2 += s1[r];
            }
            ps += ps2;
            ps += __shfl_xor(ps, 32);
            l_r += ps;

            // ---- P -> A-frags in-register (T12: cvt_pk + permlane32_swap), then PV ----
            __builtin_amdgcn_s_setprio(1);
            {   // keys kv0..+31 (ks slices 0,1)
                unsigned int w01 = cvtpk(s0[0],  s0[1]),  w23 = cvtpk(s0[2],  s0[3]);
                unsigned int w45 = cvtpk(s0[4],  s0[5]),  w67 = cvtpk(s0[6],  s0[7]);
                unsigned int w89 = cvtpk(s0[8],  s0[9]),  wab = cvtpk(s0[10], s0[11]);
                unsigned int wcd = cvtpk(s0[12], s0[13]), wef = cvtpk(s0[14], s0[15]);
                asm("v_permlane32_swap_b32 %0, %1" : "+v"(w01), "+v"(w45));
                asm("v_permlane32_swap_b32 %0, %1" : "+v"(w23), "+v"(w67));
                asm("v_permlane32_swap_b32 %0, %1" : "+v"(w89), "+v"(wcd));
                asm("v_permlane32_swap_b32 %0, %1" : "+v"(wab), "+v"(wef));
                union { unsigned int u[4]; bf16x8 v; } f0 = {{w01, w23, w45, w67}};
                union { unsigned int u[4]; bf16x8 v; } f1 = {{w89, wab, wcd, wef}};
                bf16x8 v00 = *(const bf16x8*)&Vt[cur][l31][(hi * 8) ^ sw31];
                bf16x8 v01 = *(const bf16x8*)&Vt[cur][32 + l31][(hi * 8) ^ sw31];
                acc0 = __builtin_amdgcn_mfma_f32_32x32x16_bf16(f0.v, v00, acc0, 0, 0, 0);
                acc1 = __builtin_amdgcn_mfma_f32_32x32x16_bf16(f0.v, v01, acc1, 0, 0, 0);
                bf16x8 v10 = *(const bf16x8*)&Vt[cur][l31][(16 + hi * 8) ^ sw31];
                bf16x8 v11 = *(const bf16x8*)&Vt[cur][32 + l31][(16 + hi * 8) ^ sw31];
                acc0 = __builtin_amdgcn_mfma_f32_32x32x16_bf16(f1.v, v10, acc0, 0, 0, 0);
                acc1 = __builtin_amdgcn_mfma_f32_32x32x16_bf16(f1.v, v11, acc1, 0, 0, 0);
            }
            {   // keys kv0+32..+63 (ks slices 2,3)
                unsigned int w01 = cvtpk(s1[0],  s1[1]),  w23 = cvtpk(s1[2],  s1[3]);
                unsigned int w45 = cvtpk(s1[4],  s1[5]),  w67 = cvtpk(s1[6],  s1[7]);
                unsigned int w89 = cvtpk(s1[8],  s1[9]),  wab = cvtpk(s1[10], s1[11]);
                unsigned int wcd = cvtpk(s1[12], s1[13]), wef = cvtpk(s1[14], s1[15]);
                asm("v_permlane32_swap_b32 %0, %1" : "+v"(w01), "+v"(w45));
                asm("v_permlane32_swap_b32 %0, %1" : "+v"(w23), "+v"(w67));
                asm("v_permlane32_swap_b32 %0, %1" : "+v"(w89), "+v"(wcd));
                asm("v_permlane32_swap_b32 %0, %1" : "+v"(wab), "+v"(wef));
                union { unsigned int u[4]; bf16x8 v; } f2 = {{w01, w23, w45, w67}};
                union { unsigned int u[4]; bf16x8 v; } f3 = {{w89, wab, wcd, wef}};
                bf16x8 v20 = *(const bf16x8*)&Vt[cur][l31][(32 + hi * 8) ^ sw31];
                bf16x8 v21 = *(const bf16x8*)&Vt[cur][32 + l31][(32 + hi * 8) ^ sw31];
                acc0 = __builtin_amdgcn_mfma_f32_32x32x16_bf16(f2.v, v20, acc0, 0, 0, 0);
                acc1 = __builtin_amdgcn_mfma_f32_32x32x16_bf16(f2.v, v21, acc1, 0, 0, 0);
                bf16x8 v30 = *(const bf16x8*)&Vt[cur][l31][(48 + hi * 8) ^ sw31];
                bf16x8 v31 = *(const bf16x8*)&Vt[cur][32 + l31][(48 + hi * 8) ^ sw31];
                acc0 = __builtin_amdgcn_mfma_f32_32x32x16_bf16(f3.v, v30, acc0, 0, 0, 0);
                acc1 = __builtin_amdgcn_mfma_f32_32x32x16_bf16(f3.v, v31, acc1, 0, 0, 0);
            }
            __builtin_amdgcn_s_setprio(0);
        }
    }

    // ---- epilogue ----
    if (chunk < 8) {                          // unsplit chunk: O = acc / l
        const float inv_own = 1.0f / l_r;
        float* ob = O + qbase + (size_t)(chunk * 128 + wave * 32) * D_DIM + l31;
        #pragma unroll
        for (int r = 0; r < 16; ++r) {
            const int cr = (r & 3) + 8 * (r >> 2) + 4 * hi;
            const float inv = __shfl(inv_own, cr);
            ob[(size_t)cr * D_DIM]      = acc0[r] * inv;
            ob[(size_t)cr * D_DIM + 32] = acc1[r] * inv;
        }
    } else {                                  // split segment: raw fp32 partials
        const int seg = (t0 != 0) ? 1 : 0;
        float* pp = Pp + (size_t)((head * 8 + (chunk - 8)) * 2 + seg) * PART_FLOATS;
        if (hi == 0) {
            pp[wave * 32 + l31] = m_r;
            pp[128 + wave * 32 + l31] = l_r;
        }
        float* pb = pp + 256 + (size_t)(wave * 32) * 64 + l31;
        #pragma unroll
        for (int r = 0; r < 16; ++r) {
            const int cr = (r & 3) + 8 * (r >> 2) + 4 * hi;
            pb[(size_t)cr * 64]      = acc0[r];
            pb[(size_t)cr * 64 + 32] = acc1[r];
        }
    }
}

// ---------------- combine: merge the two partials of each split chunk ----------------
__global__ __launch_bounds__(256) void combine(const float* __restrict__ Pp,
                                               float* __restrict__ O) {
    const int head = blockIdx.y;               // 32
    const int ch   = blockIdx.x;               // 0..7 -> chunk 8+ch
    const float* PA = Pp + (size_t)((head * 8 + ch) * 2) * PART_FLOATS;
    const float* PB = PA + PART_FLOATS;
    const int row = threadIdx.x >> 1;          // 0..127
    const int c0  = (threadIdx.x & 1) << 5;    // 0, 32

    const float mA = PA[row], lA = PA[128 + row];
    const float mB = PB[row], lB = PB[128 + row];
    const float M  = fmaxf(mA, mB);
    const float wA = exp2f(mA - M), wB = exp2f(mB - M);
    const float inv = 1.0f / (lA * wA + lB * wB);

    const float* a = PA + 256 + (size_t)row * 64 + c0;
    const float* b = PB + 256 + (size_t)row * 64 + c0;
    float* o = O + (size_t)head * (S_LEN * D_DIM) + (size_t)((8 + ch) * 128 + row) * D_DIM + c0;
    #pragma unroll
    for (int i = 0; i < 8; ++i) {
        f32x4 va = *(const f32x4*)(a + 4 * i);
        f32x4 vb = *(const f32x4*)(b + 4 * i);
        f32x4 vo;
        #pragma unroll
        for (int e = 0; e < 4; ++e) vo[e] = (va[e] * wA + vb[e] * wB) * inv;
        *(f32x4*)(o + 4 * i) = vo;
    }
}

// ---------------- fallback (fp32 in-kernel staging, proven) if ws too small ----------------
__global__ __launch_bounds__(256, 4) void attn_fwd_fb(const float* __restrict__ Q,
                                                      const float* __restrict__ K,
                                                      const float* __restrict__ V,
                                                      float* __restrict__ O) {
    const int b    = blockIdx.x;
    const int xcd  = b & 7;
    const int cs   = (b >> 3) & 31;
    const int j    = b >> 8;
    const int head = xcd * 4 + (cs >> 3);
    const int slot = cs & 7;
    const int chunk = (j == 0) ? slot : (j == 1) ? (31 - slot)
                    : (j == 2) ? (slot + 8) : (23 - slot);

    const int tid  = threadIdx.x;
    const int wave = tid >> 6;
    const int lane = tid & 63;
    const int l15  = lane & 15;
    const int lhi  = lane >> 4;

    const int q0 = chunk * 64 + wave * 16;
    const size_t base = (size_t)head * (S_LEN * D_DIM);
    const float qscale = 0.125f * 1.44269504088896340736f;

    __shared__ __align__(16) __bf16 Klds[2][64][64];
    __shared__ __align__(16) __bf16 Vt[2][64][64];
    __shared__ __align__(16) __bf16 Plds[4][16][64];

    const int rk = tid >> 2;
    const int ck = (tid & 3) << 4;
    const int kp = tid & 31;
    const int dc = tid >> 5;
    const int swk = (rk & 7) << 3;

    bf16x8 qf[2];
    {
        const float* qrow = Q + base + (size_t)(q0 + l15) * D_DIM + lhi * 8;
        #pragma unroll
        for (int h = 0; h < 2; ++h) {
            f32x4 a = *(const f32x4*)(qrow + h * 32);
            f32x4 bq = *(const f32x4*)(qrow + h * 32 + 4);
            bf16x8 t;
            #pragma unroll
            for (int e = 0; e < 4; ++e) { t[e] = (__bf16)(a[e] * qscale); t[e + 4] = (__bf16)(bq[e] * qscale); }
            qf[h] = t;
        }
    }

    f32x4 acc[4];
    #pragma unroll
    for (int td = 0; td < 4; ++td) acc[td] = (f32x4){0.f, 0.f, 0.f, 0.f};
    float m_r = -1e30f, l_r = 0.f;

    f32x4 pk[4], pva[2], pvb[2];
    {
        const float* ks = K + base + (size_t)rk * D_DIM + ck;
        #pragma unroll
        for (int i = 0; i < 4; ++i) pk[i] = *(const f32x4*)(ks + 4 * i);
        const float* v0 = V + base + (size_t)(2 * kp) * D_DIM + dc * 8;
        pva[0] = *(const f32x4*)v0;           pva[1] = *(const f32x4*)(v0 + 4);
        pvb[0] = *(const f32x4*)(v0 + D_DIM); pvb[1] = *(const f32x4*)(v0 + D_DIM + 4);
        bf16x8 k0, k1;
        #pragma unroll
        for (int e = 0; e < 4; ++e) {
            k0[e] = (__bf16)pk[0][e]; k0[e + 4] = (__bf16)pk[1][e];
            k1[e] = (__bf16)pk[2][e]; k1[e + 4] = (__bf16)pk[3][e];
        }
        *(bf16x8*)&Klds[0][rk][ck ^ swk] = k0;
        *(bf16x8*)&Klds[0][rk][(ck + 8) ^ swk] = k1;
        #pragma unroll
        for (int jj = 0; jj < 8; ++jj) {
            const int d = dc * 8 + jj;
            const float av = (jj < 4) ? pva[0][jj & 3] : pva[1][jj & 3];
            const float bv = (jj < 4) ? pvb[0][jj & 3] : pvb[1][jj & 3];
            union { __bf16 h[2]; unsigned int u; } t;
            t.h[0] = (__bf16)av; t.h[1] = (__bf16)bv;
            *(unsigned int*)&Vt[0][d][(2 * kp) ^ ((d & 7) << 3)] = t.u;
        }
    }

    const int nt = chunk + 1;
    for (int kt = 0; kt < nt; ++kt) {
        const int cur = kt & 1;
        __syncthreads();
        const bool pre = (kt + 1 < nt);
        if (pre) {
            const int kv1 = (kt + 1) << 6;
            const float* ks = K + base + (size_t)(kv1 + rk) * D_DIM + ck;
            #pragma unroll
            for (int i = 0; i < 4; ++i) pk[i] = *(const f32x4*)(ks + 4 * i);
            const float* v0 = V + base + (size_t)(kv1 + 2 * kp) * D_DIM + dc * 8;
            pva[0] = *(const f32x4*)v0;           pva[1] = *(const f32x4*)(v0 + 4);
            pvb[0] = *(const f32x4*)(v0 + D_DIM); pvb[1] = *(const f32x4*)(v0 + D_DIM + 4);
        }

        f32x4 s[4];
        #pragma unroll
        for (int ct = 0; ct < 4; ++ct) s[ct] = (f32x4){0.f, 0.f, 0.f, 0.f};
        #pragma unroll
        for (int h = 0; h < 2; ++h) {
            #pragma unroll
            for (int ct = 0; ct < 4; ++ct) {
                const int krow = ct * 16 + l15;
                bf16x8 kf = *(const bf16x8*)&Klds[cur][krow][(h * 32 + lhi * 8) ^ ((l15 & 7) << 3)];
                s[ct] = __builtin_amdgcn_mfma_f32_16x16x32_bf16(kf, qf[h], s[ct], 0, 0, 0);
            }
        }

        if (kt == nt - 1) {
            const int kv0 = kt << 6;
            const int qg = q0 + l15;
            #pragma unroll
            for (int ct = 0; ct < 4; ++ct)
                #pragma unroll
                for (int r = 0; r < 4; ++r) {
                    const int kg = kv0 + ct * 16 + lhi * 4 + r;
                    if (kg > qg) s[ct][r] = -1e30f;
                }
        }

        float mm = fmaxf(fmaxf(fmaxf(s[0][0], s[0][1]), fmaxf(s[0][2], s[0][3])),
                         fmaxf(fmaxf(s[1][0], s[1][1]), fmaxf(s[1][2], s[1][3])));
        mm = fmaxf(mm, fmaxf(fmaxf(fmaxf(s[2][0], s[2][1]), fmaxf(s[2][2], s[2][3])),
                             fmaxf(fmaxf(s[3][0], s[3][1]), fmaxf(s[3][2], s[3][3]))));
        mm = fmaxf(mm, __shfl_xor(mm, 16));
        mm = fmaxf(mm, __shfl_xor(mm, 32));
        if (!__all(mm - m_r <= 8.0f)) {
            const float mn = fmaxf(m_r, mm);
            const float f = exp2f(m_r - mn);
            m_r = mn;
            l_r *= f;
            #pragma unroll
            for (int r = 0; r < 4; ++r) {
                const float fr = __shfl(f, lhi * 4 + r);
                #pragma unroll
                for (int td = 0; td < 4; ++td) acc[td][r] *= fr;
            }
        }
        float ps = 0.f;
        #pragma unroll
        for (int ct = 0; ct < 4; ++ct)
            #pragma unroll
            for (int r = 0; r < 4; ++r) {
                const float p = exp2f(s[ct][r] - m_r);
                s[ct][r] = p;
                ps += p;
            }
        ps += __shfl_xor(ps, 16);
        ps += __shfl_xor(ps, 32);
        l_r += ps;

        #pragma unroll
        for (int ct = 0; ct < 4; ++ct) {
            union { __bf16 h[4]; unsigned long long u; } pw;
            #pragma unroll
            for (int r = 0; r < 4; ++r) pw.h[r] = (__bf16)s[ct][r];
            *(unsigned long long*)&Plds[wave][l15][(ct * 16 + lhi * 4) ^ ((l15 & 7) << 3)] = pw.u;
        }
        asm volatile("s_waitcnt lgkmcnt(0)" ::: "memory");
        bf16x8 pf[2];
        #pragma unroll
        for (int kh = 0; kh < 2; ++kh)
            pf[kh] = *(const bf16x8*)&Plds[wave][l15][(kh * 32 + lhi * 8) ^ ((l15 & 7) << 3)];
        asm volatile("" ::: "memory");

        #pragma unroll
        for (int kh = 0; kh < 2; ++kh) {
            #pragma unroll
            for (int td = 0; td < 4; ++td) {
                const int vrow = td * 16 + l15;
                bf16x8 vf = *(const bf16x8*)&Vt[cur][vrow][(kh * 32 + lhi * 8) ^ ((vrow & 7) << 3)];
                acc[td] = __builtin_amdgcn_mfma_f32_16x16x32_bf16(pf[kh], vf, acc[td], 0, 0, 0);
            }
        }

        if (pre) {
            const int nxt = cur ^ 1;
            bf16x8 k0, k1;
            #pragma unroll
            for (int e = 0; e < 4; ++e) {
                k0[e] = (__bf16)pk[0][e]; k0[e + 4] = (__bf16)pk[1][e];
                k1[e] = (__bf16)pk[2][e]; k1[e + 4] = (__bf16)pk[3][e];
            }
            *(bf16x8*)&Klds[nxt][rk][ck ^ swk] = k0;
            *(bf16x8*)&Klds[nxt][rk][(ck + 8) ^ swk] = k1;
            #pragma unroll
            for (int jj = 0; jj < 8; ++jj) {
                const int d = dc * 8 + jj;
                const float av = (jj < 4) ? pva[0][jj & 3] : pva[1][jj & 3];
                const float bv = (jj < 4) ? pvb[0][jj & 3] : pvb[1][jj & 3];
                union { __bf16 h[2]; unsigned int u; } t;
                t.h[0] = (__bf16)av; t.h[1] = (__bf16)bv;
                *(unsigned int*)&Vt[nxt][d][(2 * kp) ^ ((d & 7) << 3)] = t.u;
            }
        }
    }

    float* orow = O + base + (size_t)q0 * D_DIM;
    #pragma unroll
    for (int r = 0; r < 4; ++r) {
        const float inv = 1.0f / __shfl(l_r, lhi * 4 + r);
        #pragma unroll
        for (int td = 0; td < 4; ++td)
            orow[(size_t)(lhi * 4 + r) * D_DIM + td * 16 + l15] = acc[td][r] * inv;
    }
}

extern "C" void kernel_launch(void* const* d_in, const int* in_sizes, int n_in,
                              void* d_out, int out_size, void* d_ws, size_t ws_size,
                              hipStream_t stream) {
    const float* q = (const float*)d_in[0];
    const float* k = (const float*)d_in[1];
    const float* v = (const float*)d_in[2];
    float* o = (float*)d_out;
    const size_t elems = (size_t)NHEAD * S_LEN * D_DIM;
    const size_t kvBytes = 2 * elems * sizeof(__bf16);                          // 16 MB
    const size_t partBytes = (size_t)512 * PART_FLOATS * sizeof(float);         // ~17.3 MB
    if (ws_size >= kvBytes + partBytes) {
        __bf16* Kb  = (__bf16*)d_ws;
        __bf16* Vtg = Kb + elems;
        float* Pp   = (float*)((char*)d_ws + kvBytes);
        convert_kv<<<dim3(32, 32), dim3(256), 0, stream>>>(k, v, Kb, Vtg);
        attn32<<<dim3(768), dim3(256), 0, stream>>>(q, Kb, Vtg, o, Pp);
        combine<<<dim3(8, 32), dim3(256), 0, stream>>>(Pp, o);
    } else {
        attn_fwd_fb<<<dim3(1024), dim3(256), 0, stream>>>(q, k, v, o);
    }
}